// Round 10
// baseline (464.986 us; speedup 1.0000x reference)
//
#include <hip/hip_runtime.h>
#include <stdint.h>

typedef __attribute__((ext_vector_type(4))) float f32x4;
typedef __attribute__((ext_vector_type(8))) short s16x8;
typedef __attribute__((ext_vector_type(4))) int i32x4;

#define TOKENS 16384
#define IN_F 4096
#define OUT_F 4096
#define RNK 16
#define BM 128
#define BN 128
#define BKB 128               // K-tile in BYTES per row (=128 int8)
#define NTILE (IN_F / BKB)    // 32 K-tiles

static __device__ __forceinline__ unsigned short f32_to_bf16(float f) {
    uint32_t u = __builtin_bit_cast(uint32_t, f);
    uint32_t r = (u + 0x7FFFu + ((u >> 16) & 1u)) >> 16;
    return (unsigned short)r;
}

static __device__ __forceinline__ void direct_load16(const void* g, void* l) {
    __builtin_amdgcn_global_load_lds(
        (const __attribute__((address_space(1))) void*)(uintptr_t)g,
        (__attribute__((address_space(3))) void*)(uintptr_t)l,
        16, 0, 0);
}

static __device__ __forceinline__ i32x4 mfma_i8(i32x4 a, i32x4 b, i32x4 c) {
    return __builtin_amdgcn_mfma_i32_16x16x64_i8(a, b, c, 0, 0, 0);
}
static __device__ __forceinline__ f32x4 mfma16(s16x8 a, s16x8 b, f32x4 c) {
    return __builtin_amdgcn_mfma_f32_16x16x32_bf16(a, b, c, 0, 0, 0);
}

#define BAR() asm volatile("s_barrier" ::: "memory")
#define VM(n) asm volatile("s_waitcnt vmcnt(" #n ")" ::: "memory")
#define LGKM0()                                                  \
    do {                                                         \
        asm volatile("s_waitcnt lgkmcnt(0)" ::: "memory");       \
        __builtin_amdgcn_sched_barrier(0);                       \
    } while (0)
#define LGKM4() asm volatile("s_waitcnt lgkmcnt(4)" ::: "memory")

// ---------------- Kernel A: per-row absmax int8 quant of W -> wq int8 + wscale, + lora_b transpose ----------------
__global__ __launch_bounds__(256) void qd_weight_kernel(const float* __restrict__ w,
                                                        const float* __restrict__ lb,
                                                        uint32_t* __restrict__ wq,
                                                        float* __restrict__ wscale,
                                                        unsigned short* __restrict__ lbt) {
    const int row = blockIdx.x;
    const int tid = threadIdx.x;
    const float* wr = w + (size_t)row * IN_F;
    f32x4 v[4];
#pragma unroll
    for (int p = 0; p < 4; ++p)
        v[p] = *(const f32x4*)(wr + (size_t)(tid + p * 256) * 4);
    float m = 0.f;
#pragma unroll
    for (int p = 0; p < 4; ++p)
#pragma unroll
        for (int e = 0; e < 4; ++e)
            m = fmaxf(m, fabsf(v[p][e]));
#pragma unroll
    for (int off = 1; off < 64; off <<= 1)
        m = fmaxf(m, __shfl_xor(m, off, 64));
    __shared__ float red[4];
    if ((tid & 63) == 0) red[tid >> 6] = m;
    __syncthreads();
    m = fmaxf(fmaxf(red[0], red[1]), fmaxf(red[2], red[3]));
    const float scale = m * (1.0f / 127.0f);
    const float denom = scale + 1e-8f;
#pragma unroll
    for (int p = 0; p < 4; ++p) {
        uint32_t pack = 0;
#pragma unroll
        for (int e = 0; e < 4; ++e) {
            float q = rintf(v[p][e] / denom);  // RNE, matches jnp.round
            q = fminf(fmaxf(q, -128.f), 127.f);
            pack |= ((uint32_t)(uint8_t)(int)q) << (8 * e);
        }
        wq[(size_t)row * (IN_F / 4) + tid + p * 256] = pack;
    }
    if (tid == 0) wscale[row] = scale;
    if (tid < RNK)
        lbt[(size_t)row * RNK + tid] = f32_to_bf16(lb[(size_t)tid * OUT_F + row]);
}

// ---------------- Kernel A2: quantize lora_a per-r column -> la_qT[16][4096] int8 + lascale ----------------
__global__ __launch_bounds__(256) void laq_kernel(const float* __restrict__ la,
                                                  char* __restrict__ laqT,
                                                  float* __restrict__ lascale) {
    const int r = blockIdx.x;
    const int tid = threadIdx.x;
    float v[16];
#pragma unroll
    for (int j = 0; j < 16; ++j)
        v[j] = la[(size_t)(tid + j * 256) * RNK + r];
    float m = 0.f;
#pragma unroll
    for (int j = 0; j < 16; ++j) m = fmaxf(m, fabsf(v[j]));
#pragma unroll
    for (int off = 1; off < 64; off <<= 1)
        m = fmaxf(m, __shfl_xor(m, off, 64));
    __shared__ float red[4];
    if ((tid & 63) == 0) red[tid >> 6] = m;
    __syncthreads();
    m = fmaxf(fmaxf(red[0], red[1]), fmaxf(red[2], red[3]));
    m = fmaxf(m, 1e-12f);
    const float inv = 127.0f / m;
    if (tid == 0) lascale[r] = m * (1.0f / 127.0f);
#pragma unroll
    for (int j = 0; j < 16; ++j) {
        float q = fminf(fmaxf(rintf(v[j] * inv), -128.f), 127.f);
        laqT[(size_t)r * IN_F + tid + j * 256] = (char)(int)q;
    }
}

// ------------- Kernel B1: per-token absmax + int8 quantize (x read once, register-cached) -------------
__global__ __launch_bounds__(256) void xquant_kernel(const float* __restrict__ x,
                                                     uint32_t* __restrict__ xqw,
                                                     float* __restrict__ xscale) {
    const int lane = threadIdx.x & 63;
    const int t = blockIdx.x * 4 + (threadIdx.x >> 6);
    const float* xr = x + (size_t)t * IN_F;

    f32x4 xv[16];
#pragma unroll
    for (int j = 0; j < 16; ++j)
        xv[j] = *(const f32x4*)(xr + j * 256 + lane * 4);

    float m = 0.f;
#pragma unroll
    for (int j = 0; j < 16; ++j)
#pragma unroll
        for (int e = 0; e < 4; ++e) m = fmaxf(m, fabsf(xv[j][e]));
#pragma unroll
    for (int off = 1; off < 64; off <<= 1)
        m = fmaxf(m, __shfl_xor(m, off, 64));
    m = fmaxf(m, 1e-6f);
    const float inv = 127.0f / m;
    if (lane == 0) xscale[t] = m * (1.0f / 127.0f);

#pragma unroll
    for (int j = 0; j < 16; ++j) {
        uint32_t pack = 0;
#pragma unroll
        for (int e = 0; e < 4; ++e) {
            float q = fminf(fmaxf(rintf(xv[j][e] * inv), -128.f), 127.f);
            pack |= ((uint32_t)(uint8_t)(int)q) << (8 * e);
        }
        xqw[(size_t)t * (IN_F / 4) + j * 64 + lane] = pack;
    }
}

// ------------- Kernel B2: t = bf16(2 * xscale * lascale * (xq @ laqT^T)) via i8 MFMA -------------
__global__ __launch_bounds__(256) void lora_t_kernel(const char* __restrict__ xq,
                                                     const char* __restrict__ laqT,
                                                     const float* __restrict__ xscale,
                                                     const float* __restrict__ lascale,
                                                     unsigned short* __restrict__ tbf) {
    const int tid = threadIdx.x;
    const int lane = tid & 63;
    const int wid = tid >> 6;
    const int t0 = blockIdx.x * 64 + wid * 16;
    const int lrow = lane & 15;
    const int lko = lane >> 4;

    const char* pA = xq + (size_t)(t0 + lrow) * IN_F + lko * 16;
    const char* pB = laqT + (size_t)lrow * IN_F + lko * 16;

    i32x4 acc = {0, 0, 0, 0};
#pragma unroll 8
    for (int it = 0; it < IN_F / 64; ++it) {
        i32x4 a = *(const i32x4*)(pA + it * 64);
        i32x4 b = *(const i32x4*)(pB + it * 64);
        acc = mfma_i8(a, b, acc);
    }

    const float ls = lascale[lrow];
    const f32x4 xs = *(const f32x4*)(xscale + t0 + lko * 4);
#pragma unroll
    for (int q = 0; q < 4; ++q)
        tbf[(size_t)(t0 + lko * 4 + q) * RNK + lrow] =
            f32_to_bf16(2.0f * xs[q] * ls * (float)acc[q]);
}

// ------------- Kernel C: 8-phase 128x128 i8 MFMA GEMM, 4 waves, 2 blocks/CU (dual barrier domains) -------------
// 256 thr = 4 waves (2M x 2N), wave-tile 64x64. LDS 64KB -> 2 blocks co-resident per CU so one
// block's MFMA phases mask the other's LDS/stage phases. Ledger identical to the proven 256² version.
__global__ __launch_bounds__(256, 2) void gemm8p_i8_kernel(const char* __restrict__ xq,
                                                           const char* __restrict__ wq,
                                                           const float* __restrict__ xscale,
                                                           const float* __restrict__ wscale,
                                                           const unsigned short* __restrict__ tbf,
                                                           const unsigned short* __restrict__ lbt,
                                                           float* __restrict__ out) {
    __shared__ char lds[65536];  // A-slot0 | A-slot1 | B-slot0 | B-slot1, 16KB each

    const int bid = blockIdx.x;
    const int swz = (bid & 7) * 512 + (bid >> 3);  // bijective XCD swizzle (4096 % 8 == 0)
    const int tm = swz & 127, tn = swz >> 7;
    const int brow = tm * BM, bcol = tn * BN;

    const int tid = threadIdx.x;
    const int lane = tid & 63;
    const int wid = tid >> 6;
    const int wm = wid >> 1, wn = wid & 1;
    const int lrow = lane & 15;
    const int lko = lane >> 4;

    const int s_r = tid >> 3;                                    // 0..31
    const int scb = ((tid & 7) * 16) ^ (((tid >> 3) & 7) << 4);  // swizzled col-byte (proven)
    const char* gA = xq + (size_t)(brow + s_r) * IN_F + scb;
    const char* gB = wq + (size_t)(bcol + s_r) * IN_F + scb;

    char* const sA0 = (char*)lds;
    char* const sA1 = (char*)lds + 16384;
    char* const sB0 = (char*)lds + 32768;
    char* const sB1 = (char*)lds + 49152;

    const int aBase = (wm * 64 + lrow) * 128;
    const int bBase = (wn * 64 + lrow) * 128;
    const int koff[2] = {(lko * 16) ^ ((lrow & 7) << 4),
                         ((lko * 16) | 64) ^ ((lrow & 7) << 4)};

    i32x4 acc[4][4];
#pragma unroll
    for (int mf = 0; mf < 4; ++mf)
#pragma unroll
        for (int nf = 0; nf < 4; ++nf)
#pragma unroll
            for (int q = 0; q < 4; ++q) acc[mf][nf][q] = 0;

// half-tile stage: 64 rows x 128 B, 2 gloads (rows half*64+0..31, +32..63), linear dest tid*16
#define STAGE_A(kk, base, half)                                                                      \
    do {                                                                                             \
        direct_load16(gA + (size_t)((half) * 64) * IN_F + (kk), (base) + (half) * 8192 + tid * 16);  \
        direct_load16(gA + (size_t)((half) * 64 + 32) * IN_F + (kk),                                 \
                      (base) + (half) * 8192 + 4096 + tid * 16);                                     \
    } while (0)
#define STAGE_B(kk, base, half)                                                                      \
    do {                                                                                             \
        direct_load16(gB + (size_t)((half) * 64) * IN_F + (kk), (base) + (half) * 8192 + tid * 16);  \
        direct_load16(gB + (size_t)((half) * 64 + 32) * IN_F + (kk),                                 \
                      (base) + (half) * 8192 + 4096 + tid * 16);                                     \
    } while (0)

#define READ_AL(Ab)                                                          \
    _Pragma("unroll") for (int mf = 0; mf < 2; ++mf) {                       \
        aL[mf][0] = *(const i32x4*)((Ab) + aBase + mf * 2048 + koff[0]);     \
        aL[mf][1] = *(const i32x4*)((Ab) + aBase + mf * 2048 + koff[1]);     \
    }
#define READ_AH(Ab)                                                               \
    _Pragma("unroll") for (int mf = 0; mf < 2; ++mf) {                            \
        aH[mf][0] = *(const i32x4*)((Ab) + aBase + (2 + mf) * 2048 + koff[0]);    \
        aH[mf][1] = *(const i32x4*)((Ab) + aBase + (2 + mf) * 2048 + koff[1]);    \
    }
#define READ_BL(Bb)                                                          \
    _Pragma("unroll") for (int nf = 0; nf < 2; ++nf) {                       \
        bL[nf][0] = *(const i32x4*)((Bb) + bBase + nf * 2048 + koff[0]);     \
        bL[nf][1] = *(const i32x4*)((Bb) + bBase + nf * 2048 + koff[1]);     \
    }
#define READ_BH(Bb)                                                               \
    _Pragma("unroll") for (int nf = 0; nf < 2; ++nf) {                            \
        bH[nf][0] = *(const i32x4*)((Bb) + bBase + (2 + nf) * 2048 + koff[0]);    \
        bH[nf][1] = *(const i32x4*)((Bb) + bBase + (2 + nf) * 2048 + koff[1]);    \
    }
#define QUAD(MB, NB, AF, BF)                                                  \
    do {                                                                      \
        __builtin_amdgcn_s_setprio(1);                                        \
        _Pragma("unroll") for (int mf = 0; mf < 2; ++mf)                      \
            _Pragma("unroll") for (int nf = 0; nf < 2; ++nf) {                \
            acc[(MB) + mf][(NB) + nf] =                                       \
                mfma_i8(AF[mf][0], BF[nf][0], acc[(MB) + mf][(NB) + nf]);     \
            acc[(MB) + mf][(NB) + nf] =                                       \
                mfma_i8(AF[mf][1], BF[nf][1], acc[(MB) + mf][(NB) + nf]);     \
        }                                                                     \
        __builtin_amdgcn_s_setprio(0);                                        \
    } while (0)

    // ---- prologue: tile0 (4 halves) + tile1's B (2 halves); force tile0 landed ----
    STAGE_A(0, sA0, 0);
    STAGE_A(0, sA0, 1);
    STAGE_B(0, sB0, 0);
    STAGE_B(0, sB0, 1);
    STAGE_B(BKB, sB1, 0);
    STAGE_B(BKB, sB1, 1);
    VM(4);  // 12 glds issued; oldest 8 (tile0) landed, tile1-B 4 in flight
    BAR();

    i32x4 aL[2][2], aH[2][2], bL[2][2], bH[2][2];

    for (int i = 0; i < NTILE / 2; ++i) {
        const int t = 2 * i;
        const int kk1 = (t + 1) * BKB, kk2 = (t + 2) * BKB, kk3 = (t + 3) * BKB;
        const bool pf = (t + 2 < NTILE);

        // ===== ph1: read aL,bL(t)@slot0 | stage A-half0(t+1)->slot1 | Q(m01 x n01) =====
        READ_AL(sA0);
        READ_BL(sB0);
        STAGE_A(kk1, sA1, 0);
        LGKM4();
        BAR();
        LGKM0();
        QUAD(0, 0, aL, bL);
        BAR();

        // ===== ph2: read bH(t) | stage A-half1(t+1)->slot1 | Q(m01 x n23) =====
        READ_BH(sB0);
        STAGE_A(kk1, sA1, 1);
        BAR();
        LGKM0();
        QUAD(0, 2, aL, bH);
        BAR();

        // ===== ph3: read aH(t) | stage B-half0(t+2)->slot0 | Q(m23 x n23) =====
        READ_AH(sA0);
        if (pf) STAGE_B(kk2, sB0, 0);
        BAR();
        LGKM0();
        QUAD(2, 2, aH, bH);
        BAR();

        // ===== ph4: stage B-half1(t+2)->slot0 | vmcnt gate | Q(m23 x n01) =====
        if (pf) {
            STAGE_B(kk2, sB0, 1);
            VM(4);  // A(t+1) + B(t+1) landed; t+2's 4 stay in flight
        } else {
            VM(0);
        }
        BAR();
        QUAD(2, 0, aH, bL);
        BAR();

        // ===== ph5: read aL,bL(t+1)@slot1 | stage A-half0(t+2)->slot0 | Q(m01 x n01) =====
        READ_AL(sA1);
        READ_BL(sB1);
        if (pf) STAGE_A(kk2, sA0, 0);
        LGKM4();
        BAR();
        LGKM0();
        QUAD(0, 0, aL, bL);
        BAR();

        // ===== ph6: read bH(t+1) | stage A-half1(t+2)->slot0 | Q(m01 x n23) =====
        READ_BH(sB1);
        if (pf) STAGE_A(kk2, sA0, 1);
        BAR();
        LGKM0();
        QUAD(0, 2, aL, bH);
        BAR();

        // ===== ph7: read aH(t+1) | stage B-half0(t+3)->slot1 | Q(m23 x n23) =====
        READ_AH(sA1);
        if (pf) STAGE_B(kk3, sB1, 0);
        BAR();
        LGKM0();
        QUAD(2, 2, aH, bH);
        BAR();

        // ===== ph8: stage B-half1(t+3)->slot1 | vmcnt gate | Q(m23 x n01) =====
        if (pf) STAGE_B(kk3, sB1, 1);
        VM(4);  // tile t+2 landed for next ph1; trivial on final iter
        BAR();
        QUAD(2, 0, aH, bL);
        BAR();
    }
#undef STAGE_A
#undef STAGE_B
#undef READ_AL
#undef READ_AH
#undef READ_BL
#undef READ_BH
#undef QUAD

    // ---- epilogue: lora tiles to LDS (bf16), scales, combine ----
    __syncthreads();
    unsigned short* tls = (unsigned short*)lds;           // [128][16] bf16 t (prescaled by 2)
    unsigned short* lls = (unsigned short*)(lds + 4096);  // [128][16] bf16 lbt
    {
        const int row = tid >> 1, h = tid & 1;
        *(s16x8*)(tls + row * 16 + h * 8) = *(const s16x8*)(tbf + (size_t)(brow + row) * RNK + h * 8);
        *(s16x8*)(lls + row * 16 + h * 8) = *(const s16x8*)(lbt + (size_t)(bcol + row) * RNK + h * 8);
    }
    __syncthreads();

    const int c0 = bcol + wn * 64 + lrow;
    const int r0base = brow + wm * 64 + lko * 4;

    s16x8 z;
#pragma unroll
    for (int e = 0; e < 8; ++e) z[e] = 0;
    s16x8 at8[4], bl8[4];
#pragma unroll
    for (int mf = 0; mf < 4; ++mf) {
        const int row = wm * 64 + mf * 16 + lrow;
        at8[mf] = (lko < 2) ? *(const s16x8*)(tls + row * 16 + lko * 8) : z;
    }
#pragma unroll
    for (int nf = 0; nf < 4; ++nf) {
        const int row = wn * 64 + nf * 16 + lrow;
        bl8[nf] = (lko < 2) ? *(const s16x8*)(lls + row * 16 + lko * 8) : z;
    }
    float ws4[4];
#pragma unroll
    for (int nf = 0; nf < 4; ++nf) ws4[nf] = wscale[c0 + nf * 16];

    const f32x4 zf = {0.f, 0.f, 0.f, 0.f};
#pragma unroll
    for (int mf = 0; mf < 4; ++mf) {
        f32x4 lor[4];
#pragma unroll
        for (int nf = 0; nf < 4; ++nf) lor[nf] = mfma16(at8[mf], bl8[nf], zf);
        const f32x4 xs4 = *(const f32x4*)(xscale + r0base + mf * 16);
#pragma unroll
        for (int q = 0; q < 4; ++q) {
            float* orow = out + (size_t)(r0base + mf * 16 + q) * OUT_F;
#pragma unroll
            for (int nf = 0; nf < 4; ++nf)
                orow[c0 + nf * 16] =
                    xs4[q] * ws4[nf] * (float)acc[mf][nf][q] + lor[nf][q];
        }
    }
}

extern "C" void kernel_launch(void* const* d_in, const int* in_sizes, int n_in,
                              void* d_out, int out_size, void* d_ws, size_t ws_size,
                              hipStream_t stream) {
    const float* x  = (const float*)d_in[0];
    const float* w  = (const float*)d_in[1];
    const float* la = (const float*)d_in[2];
    const float* lb = (const float*)d_in[3];
    float* out = (float*)d_out;

    char* ws = (char*)d_ws;
    size_t off = 0;
    char* xq = ws + off;                 off += (size_t)TOKENS * IN_F;      // 64 MiB
    char* wqb = ws + off;                off += (size_t)OUT_F * IN_F;       // 16 MiB
    unsigned short* tbf = (unsigned short*)(ws + off); off += (size_t)TOKENS * RNK * 2;  // 512 KiB
    unsigned short* lbt = (unsigned short*)(ws + off); off += (size_t)OUT_F * RNK * 2;   // 128 KiB
    float* xscale = (float*)(ws + off);  off += (size_t)TOKENS * 4;         // 64 KiB
    float* wscale = (float*)(ws + off);  off += (size_t)OUT_F * 4;          // 16 KiB
    char* laqT = ws + off;               off += (size_t)RNK * IN_F;         // 64 KiB
    float* lascale = (float*)(ws + off); off += RNK * 4;

    qd_weight_kernel<<<OUT_F, 256, 0, stream>>>(w, lb, (uint32_t*)wqb, wscale, lbt);
    laq_kernel<<<RNK, 256, 0, stream>>>(la, laqT, lascale);
    xquant_kernel<<<TOKENS / 4, 256, 0, stream>>>(x, (uint32_t*)xq, xscale);
    lora_t_kernel<<<TOKENS / 64, 256, 0, stream>>>(xq, laqT, xscale, lascale, tbf);
    gemm8p_i8_kernel<<<(TOKENS / BM) * (OUT_F / BN), 256, 0, stream>>>(
        xq, wqb, xscale, wscale, tbf, lbt, out);
}

// Round 11
// 399.345 us; speedup vs baseline: 1.1644x; 1.1644x over previous
//
#include <hip/hip_runtime.h>
#include <stdint.h>

typedef __attribute__((ext_vector_type(4))) float f32x4;
typedef __attribute__((ext_vector_type(8))) short s16x8;
typedef __attribute__((ext_vector_type(4))) int i32x4;

#define TOKENS 16384
#define IN_F 4096
#define OUT_F 4096
#define RNK 16
#define BM 256
#define BN 256
#define BKB 128               // K-tile in BYTES per row (=128 int8)
#define NTILE (IN_F / BKB)    // 32 K-tiles

static __device__ __forceinline__ unsigned short f32_to_bf16(float f) {
    uint32_t u = __builtin_bit_cast(uint32_t, f);
    uint32_t r = (u + 0x7FFFu + ((u >> 16) & 1u)) >> 16;
    return (unsigned short)r;
}

static __device__ __forceinline__ void direct_load16(const void* g, void* l) {
    __builtin_amdgcn_global_load_lds(
        (const __attribute__((address_space(1))) void*)(uintptr_t)g,
        (__attribute__((address_space(3))) void*)(uintptr_t)l,
        16, 0, 0);
}

static __device__ __forceinline__ i32x4 mfma_i8(i32x4 a, i32x4 b, i32x4 c) {
    return __builtin_amdgcn_mfma_i32_16x16x64_i8(a, b, c, 0, 0, 0);
}
static __device__ __forceinline__ f32x4 mfma16(s16x8 a, s16x8 b, f32x4 c) {
    return __builtin_amdgcn_mfma_f32_16x16x32_bf16(a, b, c, 0, 0, 0);
}

#define BAR() asm volatile("s_barrier" ::: "memory")
#define VM(n) asm volatile("s_waitcnt vmcnt(" #n ")" ::: "memory")
#define LGKM0()                                                  \
    do {                                                         \
        asm volatile("s_waitcnt lgkmcnt(0)" ::: "memory");       \
        __builtin_amdgcn_sched_barrier(0);                       \
    } while (0)
#define LGKM8() asm volatile("s_waitcnt lgkmcnt(8)" ::: "memory")

// ---------------- Kernel A: per-row absmax int8 quant of W -> wq int8 + wscale, + lora_b transpose ----------------
__global__ __launch_bounds__(256) void qd_weight_kernel(const float* __restrict__ w,
                                                        const float* __restrict__ lb,
                                                        uint32_t* __restrict__ wq,
                                                        float* __restrict__ wscale,
                                                        unsigned short* __restrict__ lbt) {
    const int row = blockIdx.x;
    const int tid = threadIdx.x;
    const float* wr = w + (size_t)row * IN_F;
    f32x4 v[4];
#pragma unroll
    for (int p = 0; p < 4; ++p)
        v[p] = *(const f32x4*)(wr + (size_t)(tid + p * 256) * 4);
    float m = 0.f;
#pragma unroll
    for (int p = 0; p < 4; ++p)
#pragma unroll
        for (int e = 0; e < 4; ++e)
            m = fmaxf(m, fabsf(v[p][e]));
#pragma unroll
    for (int off = 1; off < 64; off <<= 1)
        m = fmaxf(m, __shfl_xor(m, off, 64));
    __shared__ float red[4];
    if ((tid & 63) == 0) red[tid >> 6] = m;
    __syncthreads();
    m = fmaxf(fmaxf(red[0], red[1]), fmaxf(red[2], red[3]));
    const float scale = m * (1.0f / 127.0f);
    const float denom = scale + 1e-8f;
#pragma unroll
    for (int p = 0; p < 4; ++p) {
        uint32_t pack = 0;
#pragma unroll
        for (int e = 0; e < 4; ++e) {
            float q = rintf(v[p][e] / denom);  // RNE, matches jnp.round
            q = fminf(fmaxf(q, -128.f), 127.f);
            pack |= ((uint32_t)(uint8_t)(int)q) << (8 * e);
        }
        wq[(size_t)row * (IN_F / 4) + tid + p * 256] = pack;
    }
    if (tid == 0) wscale[row] = scale;
    if (tid < RNK)
        lbt[(size_t)row * RNK + tid] = f32_to_bf16(lb[(size_t)tid * OUT_F + row]);
}

// ---------------- Kernel A2: quantize lora_a per-r column -> la_qT[16][4096] int8 + lascale ----------------
__global__ __launch_bounds__(256) void laq_kernel(const float* __restrict__ la,
                                                  char* __restrict__ laqT,
                                                  float* __restrict__ lascale) {
    const int r = blockIdx.x;
    const int tid = threadIdx.x;
    float v[16];
#pragma unroll
    for (int j = 0; j < 16; ++j)
        v[j] = la[(size_t)(tid + j * 256) * RNK + r];
    float m = 0.f;
#pragma unroll
    for (int j = 0; j < 16; ++j) m = fmaxf(m, fabsf(v[j]));
#pragma unroll
    for (int off = 1; off < 64; off <<= 1)
        m = fmaxf(m, __shfl_xor(m, off, 64));
    __shared__ float red[4];
    if ((tid & 63) == 0) red[tid >> 6] = m;
    __syncthreads();
    m = fmaxf(fmaxf(red[0], red[1]), fmaxf(red[2], red[3]));
    m = fmaxf(m, 1e-12f);
    const float inv = 127.0f / m;
    if (tid == 0) lascale[r] = m * (1.0f / 127.0f);
#pragma unroll
    for (int j = 0; j < 16; ++j) {
        float q = fminf(fmaxf(rintf(v[j] * inv), -128.f), 127.f);
        laqT[(size_t)r * IN_F + tid + j * 256] = (char)(int)q;
    }
}

// ------------- Kernel B1: per-token absmax + int8 quantize (x read once, register-cached) -------------
__global__ __launch_bounds__(256) void xquant_kernel(const float* __restrict__ x,
                                                     uint32_t* __restrict__ xqw,
                                                     float* __restrict__ xscale) {
    const int lane = threadIdx.x & 63;
    const int t = blockIdx.x * 4 + (threadIdx.x >> 6);
    const float* xr = x + (size_t)t * IN_F;

    f32x4 xv[16];
#pragma unroll
    for (int j = 0; j < 16; ++j)
        xv[j] = *(const f32x4*)(xr + j * 256 + lane * 4);

    float m = 0.f;
#pragma unroll
    for (int j = 0; j < 16; ++j)
#pragma unroll
        for (int e = 0; e < 4; ++e) m = fmaxf(m, fabsf(xv[j][e]));
#pragma unroll
    for (int off = 1; off < 64; off <<= 1)
        m = fmaxf(m, __shfl_xor(m, off, 64));
    m = fmaxf(m, 1e-6f);
    const float inv = 127.0f / m;
    if (lane == 0) xscale[t] = m * (1.0f / 127.0f);

#pragma unroll
    for (int j = 0; j < 16; ++j) {
        uint32_t pack = 0;
#pragma unroll
        for (int e = 0; e < 4; ++e) {
            float q = fminf(fmaxf(rintf(xv[j][e] * inv), -128.f), 127.f);
            pack |= ((uint32_t)(uint8_t)(int)q) << (8 * e);
        }
        xqw[(size_t)t * (IN_F / 4) + j * 64 + lane] = pack;
    }
}

// ------------- Kernel B2: t = bf16(2 * xscale * lascale * (xq @ laqT^T)) via i8 MFMA -------------
__global__ __launch_bounds__(256) void lora_t_kernel(const char* __restrict__ xq,
                                                     const char* __restrict__ laqT,
                                                     const float* __restrict__ xscale,
                                                     const float* __restrict__ lascale,
                                                     unsigned short* __restrict__ tbf) {
    const int tid = threadIdx.x;
    const int lane = tid & 63;
    const int wid = tid >> 6;
    const int t0 = blockIdx.x * 64 + wid * 16;
    const int lrow = lane & 15;
    const int lko = lane >> 4;

    const char* pA = xq + (size_t)(t0 + lrow) * IN_F + lko * 16;
    const char* pB = laqT + (size_t)lrow * IN_F + lko * 16;

    i32x4 acc = {0, 0, 0, 0};
#pragma unroll 8
    for (int it = 0; it < IN_F / 64; ++it) {
        i32x4 a = *(const i32x4*)(pA + it * 64);
        i32x4 b = *(const i32x4*)(pB + it * 64);
        acc = mfma_i8(a, b, acc);
    }

    const float ls = lascale[lrow];
    const f32x4 xs = *(const f32x4*)(xscale + t0 + lko * 4);
#pragma unroll
    for (int q = 0; q < 4; ++q)
        tbf[(size_t)(t0 + lko * 4 + q) * RNK + lrow] =
            f32_to_bf16(2.0f * xs[q] * ls * (float)acc[q]);
}

// ------------- Kernel C: 8-phase 256x256 i8 MFMA GEMM (S = xq @ wq^T, exact i32) -------------
// Best-known configuration (R9): 512 thr, 8 waves 2Mx4N, BKB=128, dbuf 128KB LDS,
// proven 0-conflict XOR swizzle, counted vmcnt(4) gates at ph4/ph8 only.
__global__ __launch_bounds__(512, 2) void gemm8p_i8_kernel(const char* __restrict__ xq,
                                                           const char* __restrict__ wq,
                                                           const float* __restrict__ xscale,
                                                           const float* __restrict__ wscale,
                                                           const unsigned short* __restrict__ tbf,
                                                           const unsigned short* __restrict__ lbt,
                                                           float* __restrict__ out) {
    __shared__ char lds[131072];  // A-slot0 | A-slot1 | B-slot0 | B-slot1, 32KB each

    const int bid = blockIdx.x;
    const int swz = (bid & 7) * 128 + (bid >> 3);  // bijective XCD swizzle (1024 % 8 == 0)
    const int tm = swz & 63, tn = swz >> 6;
    const int brow = tm * BM, bcol = tn * BN;

    const int tid = threadIdx.x;
    const int lane = tid & 63;
    const int wid = tid >> 6;
    const int wm = wid >> 2, wn = wid & 3;
    const int lrow = lane & 15;
    const int lko = lane >> 4;

    const int s_r = tid >> 3;
    const int scb = ((tid & 7) * 16) ^ (((tid >> 3) & 7) << 4);
    const char* gA = xq + (size_t)(brow + s_r) * IN_F + scb;
    const char* gB = wq + (size_t)(bcol + s_r) * IN_F + scb;

    char* const sA0 = (char*)lds;
    char* const sA1 = (char*)lds + 32768;
    char* const sB0 = (char*)lds + 65536;
    char* const sB1 = (char*)lds + 98304;

    const int aBase = (wm * 128 + lrow) * 128;
    const int bBase = (wn * 64 + lrow) * 128;
    const int koff[2] = {(lko * 16) ^ ((lrow & 7) << 4),
                         ((lko * 16) | 64) ^ ((lrow & 7) << 4)};

    i32x4 acc[8][4];
#pragma unroll
    for (int mf = 0; mf < 8; ++mf)
#pragma unroll
        for (int nf = 0; nf < 4; ++nf)
#pragma unroll
            for (int q = 0; q < 4; ++q) acc[mf][nf][q] = 0;

#define STAGE_A(kk, base, half)                                                                       \
    do {                                                                                              \
        direct_load16(gA + (size_t)((half) * 128) * IN_F + (kk), (base) + (half) * 16384 + tid * 16); \
        direct_load16(gA + (size_t)((half) * 128 + 64) * IN_F + (kk),                                 \
                      (base) + (half) * 16384 + 8192 + tid * 16);                                     \
    } while (0)
#define STAGE_B(kk, base, half)                                                                       \
    do {                                                                                              \
        direct_load16(gB + (size_t)((half) * 128) * IN_F + (kk), (base) + (half) * 16384 + tid * 16); \
        direct_load16(gB + (size_t)((half) * 128 + 64) * IN_F + (kk),                                 \
                      (base) + (half) * 16384 + 8192 + tid * 16);                                     \
    } while (0)

#define READ_AL(Ab)                                                          \
    _Pragma("unroll") for (int mf = 0; mf < 4; ++mf) {                       \
        aL[mf][0] = *(const i32x4*)((Ab) + aBase + mf * 2048 + koff[0]);     \
        aL[mf][1] = *(const i32x4*)((Ab) + aBase + mf * 2048 + koff[1]);     \
    }
#define READ_AH(Ab)                                                               \
    _Pragma("unroll") for (int mf = 0; mf < 4; ++mf) {                            \
        aH[mf][0] = *(const i32x4*)((Ab) + aBase + (4 + mf) * 2048 + koff[0]);    \
        aH[mf][1] = *(const i32x4*)((Ab) + aBase + (4 + mf) * 2048 + koff[1]);    \
    }
#define READ_BL(Bb)                                                          \
    _Pragma("unroll") for (int nf = 0; nf < 2; ++nf) {                       \
        bL[nf][0] = *(const i32x4*)((Bb) + bBase + nf * 2048 + koff[0]);     \
        bL[nf][1] = *(const i32x4*)((Bb) + bBase + nf * 2048 + koff[1]);     \
    }
#define READ_BH(Bb)                                                               \
    _Pragma("unroll") for (int nf = 0; nf < 2; ++nf) {                            \
        bH[nf][0] = *(const i32x4*)((Bb) + bBase + (2 + nf) * 2048 + koff[0]);    \
        bH[nf][1] = *(const i32x4*)((Bb) + bBase + (2 + nf) * 2048 + koff[1]);    \
    }
#define QUAD(MB, NB, AF, BF)                                                  \
    do {                                                                      \
        __builtin_amdgcn_s_setprio(1);                                        \
        _Pragma("unroll") for (int mf = 0; mf < 4; ++mf)                      \
            _Pragma("unroll") for (int nf = 0; nf < 2; ++nf) {                \
            acc[(MB) + mf][(NB) + nf] =                                       \
                mfma_i8(AF[mf][0], BF[nf][0], acc[(MB) + mf][(NB) + nf]);     \
            acc[(MB) + mf][(NB) + nf] =                                       \
                mfma_i8(AF[mf][1], BF[nf][1], acc[(MB) + mf][(NB) + nf]);     \
        }                                                                     \
        __builtin_amdgcn_s_setprio(0);                                        \
    } while (0)

    STAGE_A(0, sA0, 0);
    STAGE_A(0, sA0, 1);
    STAGE_B(0, sB0, 0);
    STAGE_B(0, sB0, 1);
    STAGE_B(BKB, sB1, 0);
    STAGE_B(BKB, sB1, 1);
    VM(4);
    BAR();

    i32x4 aL[4][2], aH[4][2], bL[2][2], bH[2][2];

    for (int i = 0; i < NTILE / 2; ++i) {
        const int t = 2 * i;
        const int kk1 = (t + 1) * BKB, kk2 = (t + 2) * BKB, kk3 = (t + 3) * BKB;
        const bool pf = (t + 2 < NTILE);

        // ===== ph1 =====
        READ_AL(sA0);
        READ_BL(sB0);
        STAGE_A(kk1, sA1, 0);
        LGKM8();
        BAR();
        LGKM0();
        QUAD(0, 0, aL, bL);
        BAR();

        // ===== ph2 =====
        READ_BH(sB0);
        STAGE_A(kk1, sA1, 1);
        BAR();
        LGKM0();
        QUAD(0, 2, aL, bH);
        BAR();

        // ===== ph3 =====
        READ_AH(sA0);
        if (pf) STAGE_B(kk2, sB0, 0);
        BAR();
        LGKM0();
        QUAD(4, 2, aH, bH);
        BAR();

        // ===== ph4 =====
        if (pf) {
            STAGE_B(kk2, sB0, 1);
            VM(4);
        } else {
            VM(0);
        }
        BAR();
        QUAD(4, 0, aH, bL);
        BAR();

        // ===== ph5 =====
        READ_AL(sA1);
        READ_BL(sB1);
        if (pf) STAGE_A(kk2, sA0, 0);
        LGKM8();
        BAR();
        LGKM0();
        QUAD(0, 0, aL, bL);
        BAR();

        // ===== ph6 =====
        READ_BH(sB1);
        if (pf) STAGE_A(kk2, sA0, 1);
        BAR();
        LGKM0();
        QUAD(0, 2, aL, bH);
        BAR();

        // ===== ph7 =====
        READ_AH(sA1);
        if (pf) STAGE_B(kk3, sB1, 0);
        BAR();
        LGKM0();
        QUAD(4, 2, aH, bH);
        BAR();

        // ===== ph8 =====
        if (pf) STAGE_B(kk3, sB1, 1);
        VM(4);
        BAR();
        QUAD(4, 0, aH, bL);
        BAR();
    }
#undef STAGE_A
#undef STAGE_B
#undef READ_AL
#undef READ_AH
#undef READ_BL
#undef READ_BH
#undef QUAD

    // ---- epilogue: lora tiles to LDS (bf16), scales, combine ----
    __syncthreads();
    unsigned short* tls = (unsigned short*)lds;           // [256][16] bf16 t (prescaled by 2)
    unsigned short* lls = (unsigned short*)(lds + 8192);  // [256][16] bf16 lbt
    {
        const int row = tid >> 1, h = tid & 1;
        *(s16x8*)(tls + row * 16 + h * 8) = *(const s16x8*)(tbf + (size_t)(brow + row) * RNK + h * 8);
        *(s16x8*)(lls + row * 16 + h * 8) = *(const s16x8*)(lbt + (size_t)(bcol + row) * RNK + h * 8);
    }
    __syncthreads();

    const int c0 = bcol + wn * 64 + lrow;
    const int r0base = brow + wm * 128 + lko * 4;

    s16x8 z;
#pragma unroll
    for (int e = 0; e < 8; ++e) z[e] = 0;
    s16x8 at8[8], bl8[4];
#pragma unroll
    for (int mf = 0; mf < 8; ++mf) {
        const int row = wm * 128 + mf * 16 + lrow;
        at8[mf] = (lko < 2) ? *(const s16x8*)(tls + row * 16 + lko * 8) : z;
    }
#pragma unroll
    for (int nf = 0; nf < 4; ++nf) {
        const int row = wn * 64 + nf * 16 + lrow;
        bl8[nf] = (lko < 2) ? *(const s16x8*)(lls + row * 16 + lko * 8) : z;
    }
    float ws4[4];
#pragma unroll
    for (int nf = 0; nf < 4; ++nf) ws4[nf] = wscale[c0 + nf * 16];

    const f32x4 zf = {0.f, 0.f, 0.f, 0.f};
#pragma unroll
    for (int mf = 0; mf < 8; ++mf) {
        f32x4 lor[4];
#pragma unroll
        for (int nf = 0; nf < 4; ++nf) lor[nf] = mfma16(at8[mf], bl8[nf], zf);
        const f32x4 xs4 = *(const f32x4*)(xscale + r0base + mf * 16);
#pragma unroll
        for (int q = 0; q < 4; ++q) {
            float* orow = out + (size_t)(r0base + mf * 16 + q) * OUT_F;
#pragma unroll
            for (int nf = 0; nf < 4; ++nf)
                orow[c0 + nf * 16] =
                    xs4[q] * ws4[nf] * (float)acc[mf][nf][q] + lor[nf][q];
        }
    }
}

extern "C" void kernel_launch(void* const* d_in, const int* in_sizes, int n_in,
                              void* d_out, int out_size, void* d_ws, size_t ws_size,
                              hipStream_t stream) {
    const float* x  = (const float*)d_in[0];
    const float* w  = (const float*)d_in[1];
    const float* la = (const float*)d_in[2];
    const float* lb = (const float*)d_in[3];
    float* out = (float*)d_out;

    char* ws = (char*)d_ws;
    size_t off = 0;
    char* xq = ws + off;                 off += (size_t)TOKENS * IN_F;      // 64 MiB
    char* wqb = ws + off;                off += (size_t)OUT_F * IN_F;       // 16 MiB
    unsigned short* tbf = (unsigned short*)(ws + off); off += (size_t)TOKENS * RNK * 2;  // 512 KiB
    unsigned short* lbt = (unsigned short*)(ws + off); off += (size_t)OUT_F * RNK * 2;   // 128 KiB
    float* xscale = (float*)(ws + off);  off += (size_t)TOKENS * 4;         // 64 KiB
    float* wscale = (float*)(ws + off);  off += (size_t)OUT_F * 4;          // 16 KiB
    char* laqT = ws + off;               off += (size_t)RNK * IN_F;         // 64 KiB
    float* lascale = (float*)(ws + off); off += RNK * 4;

    qd_weight_kernel<<<OUT_F, 256, 0, stream>>>(w, lb, (uint32_t*)wqb, wscale, lbt);
    laq_kernel<<<RNK, 256, 0, stream>>>(la, laqT, lascale);
    xquant_kernel<<<TOKENS / 4, 256, 0, stream>>>(x, (uint32_t*)xq, xscale);
    lora_t_kernel<<<TOKENS / 64, 256, 0, stream>>>(xq, laqT, xscale, lascale, tbf);
    gemm8p_i8_kernel<<<(TOKENS / BM) * (OUT_F / BN), 512, 0, stream>>>(
        xq, wqb, xscale, wscale, tbf, lbt, out);
}

// Round 12
// 378.930 us; speedup vs baseline: 1.2271x; 1.0539x over previous
//
#include <hip/hip_runtime.h>
#include <stdint.h>

typedef __attribute__((ext_vector_type(4))) float f32x4;
typedef __attribute__((ext_vector_type(8))) short s16x8;
typedef __attribute__((ext_vector_type(4))) int i32x4;

#define TOKENS 16384
#define IN_F 4096
#define OUT_F 4096
#define RNK 16
#define BM 256
#define BN 256
#define BKB 128               // K-tile in BYTES per row (=128 int8)
#define NTILE (IN_F / BKB)    // 32 K-tiles

static __device__ __forceinline__ unsigned short f32_to_bf16(float f) {
    uint32_t u = __builtin_bit_cast(uint32_t, f);
    uint32_t r = (u + 0x7FFFu + ((u >> 16) & 1u)) >> 16;
    return (unsigned short)r;
}

static __device__ __forceinline__ void direct_load16(const void* g, void* l) {
    __builtin_amdgcn_global_load_lds(
        (const __attribute__((address_space(1))) void*)(uintptr_t)g,
        (__attribute__((address_space(3))) void*)(uintptr_t)l,
        16, 0, 0);
}

static __device__ __forceinline__ i32x4 mfma_i8(i32x4 a, i32x4 b, i32x4 c) {
    return __builtin_amdgcn_mfma_i32_16x16x64_i8(a, b, c, 0, 0, 0);
}
static __device__ __forceinline__ f32x4 mfma16(s16x8 a, s16x8 b, f32x4 c) {
    return __builtin_amdgcn_mfma_f32_16x16x32_bf16(a, b, c, 0, 0, 0);
}

#define BAR() asm volatile("s_barrier" ::: "memory")
#define VM(n) asm volatile("s_waitcnt vmcnt(" #n ")" ::: "memory")
#define LGKM0()                                                  \
    do {                                                         \
        asm volatile("s_waitcnt lgkmcnt(0)" ::: "memory");       \
        __builtin_amdgcn_sched_barrier(0);                       \
    } while (0)

// ---------------- Kernel A: per-row absmax int8 quant of W -> wq int8 + wscale, + lora_b transpose ----------------
__global__ __launch_bounds__(256) void qd_weight_kernel(const float* __restrict__ w,
                                                        const float* __restrict__ lb,
                                                        uint32_t* __restrict__ wq,
                                                        float* __restrict__ wscale,
                                                        unsigned short* __restrict__ lbt) {
    const int row = blockIdx.x;
    const int tid = threadIdx.x;
    const float* wr = w + (size_t)row * IN_F;
    f32x4 v[4];
#pragma unroll
    for (int p = 0; p < 4; ++p)
        v[p] = *(const f32x4*)(wr + (size_t)(tid + p * 256) * 4);
    float m = 0.f;
#pragma unroll
    for (int p = 0; p < 4; ++p)
#pragma unroll
        for (int e = 0; e < 4; ++e)
            m = fmaxf(m, fabsf(v[p][e]));
#pragma unroll
    for (int off = 1; off < 64; off <<= 1)
        m = fmaxf(m, __shfl_xor(m, off, 64));
    __shared__ float red[4];
    if ((tid & 63) == 0) red[tid >> 6] = m;
    __syncthreads();
    m = fmaxf(fmaxf(red[0], red[1]), fmaxf(red[2], red[3]));
    const float scale = m * (1.0f / 127.0f);
    const float denom = scale + 1e-8f;
#pragma unroll
    for (int p = 0; p < 4; ++p) {
        uint32_t pack = 0;
#pragma unroll
        for (int e = 0; e < 4; ++e) {
            float q = rintf(v[p][e] / denom);  // RNE, matches jnp.round
            q = fminf(fmaxf(q, -128.f), 127.f);
            pack |= ((uint32_t)(uint8_t)(int)q) << (8 * e);
        }
        wq[(size_t)row * (IN_F / 4) + tid + p * 256] = pack;
    }
    if (tid == 0) wscale[row] = scale;
    if (tid < RNK)
        lbt[(size_t)row * RNK + tid] = f32_to_bf16(lb[(size_t)tid * OUT_F + row]);
}

// ---------------- Kernel A2: quantize lora_a per-r column -> la_qT[16][4096] int8 + lascale ----------------
__global__ __launch_bounds__(256) void laq_kernel(const float* __restrict__ la,
                                                  char* __restrict__ laqT,
                                                  float* __restrict__ lascale) {
    const int r = blockIdx.x;
    const int tid = threadIdx.x;
    float v[16];
#pragma unroll
    for (int j = 0; j < 16; ++j)
        v[j] = la[(size_t)(tid + j * 256) * RNK + r];
    float m = 0.f;
#pragma unroll
    for (int j = 0; j < 16; ++j) m = fmaxf(m, fabsf(v[j]));
#pragma unroll
    for (int off = 1; off < 64; off <<= 1)
        m = fmaxf(m, __shfl_xor(m, off, 64));
    __shared__ float red[4];
    if ((tid & 63) == 0) red[tid >> 6] = m;
    __syncthreads();
    m = fmaxf(fmaxf(red[0], red[1]), fmaxf(red[2], red[3]));
    m = fmaxf(m, 1e-12f);
    const float inv = 127.0f / m;
    if (tid == 0) lascale[r] = m * (1.0f / 127.0f);
#pragma unroll
    for (int j = 0; j < 16; ++j) {
        float q = fminf(fmaxf(rintf(v[j] * inv), -128.f), 127.f);
        laqT[(size_t)r * IN_F + tid + j * 256] = (char)(int)q;
    }
}

// ------------- Kernel B1: per-token absmax + int8 quantize (x read once, register-cached) -------------
__global__ __launch_bounds__(256) void xquant_kernel(const float* __restrict__ x,
                                                     uint32_t* __restrict__ xqw,
                                                     float* __restrict__ xscale) {
    const int lane = threadIdx.x & 63;
    const int t = blockIdx.x * 4 + (threadIdx.x >> 6);
    const float* xr = x + (size_t)t * IN_F;

    f32x4 xv[16];
#pragma unroll
    for (int j = 0; j < 16; ++j)
        xv[j] = *(const f32x4*)(xr + j * 256 + lane * 4);

    float m = 0.f;
#pragma unroll
    for (int j = 0; j < 16; ++j)
#pragma unroll
        for (int e = 0; e < 4; ++e) m = fmaxf(m, fabsf(xv[j][e]));
#pragma unroll
    for (int off = 1; off < 64; off <<= 1)
        m = fmaxf(m, __shfl_xor(m, off, 64));
    m = fmaxf(m, 1e-6f);
    const float inv = 127.0f / m;
    if (lane == 0) xscale[t] = m * (1.0f / 127.0f);

#pragma unroll
    for (int j = 0; j < 16; ++j) {
        uint32_t pack = 0;
#pragma unroll
        for (int e = 0; e < 4; ++e) {
            float q = fminf(fmaxf(rintf(xv[j][e] * inv), -128.f), 127.f);
            pack |= ((uint32_t)(uint8_t)(int)q) << (8 * e);
        }
        xqw[(size_t)t * (IN_F / 4) + j * 64 + lane] = pack;
    }
}

// ------------- Kernel B2: t = bf16(2 * xscale * lascale * (xq @ laqT^T)) via i8 MFMA -------------
__global__ __launch_bounds__(256) void lora_t_kernel(const char* __restrict__ xq,
                                                     const char* __restrict__ laqT,
                                                     const float* __restrict__ xscale,
                                                     const float* __restrict__ lascale,
                                                     unsigned short* __restrict__ tbf) {
    const int tid = threadIdx.x;
    const int lane = tid & 63;
    const int wid = tid >> 6;
    const int t0 = blockIdx.x * 64 + wid * 16;
    const int lrow = lane & 15;
    const int lko = lane >> 4;

    const char* pA = xq + (size_t)(t0 + lrow) * IN_F + lko * 16;
    const char* pB = laqT + (size_t)lrow * IN_F + lko * 16;

    i32x4 acc = {0, 0, 0, 0};
#pragma unroll 8
    for (int it = 0; it < IN_F / 64; ++it) {
        i32x4 a = *(const i32x4*)(pA + it * 64);
        i32x4 b = *(const i32x4*)(pB + it * 64);
        acc = mfma_i8(a, b, acc);
    }

    const float ls = lascale[lrow];
    const f32x4 xs = *(const f32x4*)(xscale + t0 + lko * 4);
#pragma unroll
    for (int q = 0; q < 4; ++q)
        tbf[(size_t)(t0 + lko * 4 + q) * RNK + lrow] =
            f32_to_bf16(2.0f * xs[q] * ls * (float)acc[q]);
}

// ------------- Kernel C: 8-phase 256x256 i8 MFMA GEMM, MINIMAL-BARRIER variant -------------
// Same stage placement / vmcnt ledger / swizzle as R9 (proven). Barriers reduced 8/tile -> 2/tile:
// only the 4 load-bearing edges per 2-K-tile iteration remain:
//   BAR2: bL,bH(t) reads retired  -> STAGE_B(t+2)->sB0 may issue
//   BAR4: VM(4) collective (A(t+1),B(t+1) landed) + aL,aH(t) retired -> STAGE_A(t+2)->sA0
//   BAR6: bL,bH(t+1) retired      -> STAGE_B(t+3)->sB1
//   BAR8: VM(4) collective (A(t+2),B(t+2) landed) -> next iteration reads slot0
// Waves drift between barriers -> one wave's MFMA overlaps another's ds_read (m114 mechanism).
__global__ __launch_bounds__(512, 2) void gemm8p_i8_kernel(const char* __restrict__ xq,
                                                           const char* __restrict__ wq,
                                                           const float* __restrict__ xscale,
                                                           const float* __restrict__ wscale,
                                                           const unsigned short* __restrict__ tbf,
                                                           const unsigned short* __restrict__ lbt,
                                                           float* __restrict__ out) {
    __shared__ char lds[131072];  // A-slot0 | A-slot1 | B-slot0 | B-slot1, 32KB each

    const int bid = blockIdx.x;
    const int swz = (bid & 7) * 128 + (bid >> 3);  // bijective XCD swizzle (1024 % 8 == 0)
    const int tm = swz & 63, tn = swz >> 6;
    const int brow = tm * BM, bcol = tn * BN;

    const int tid = threadIdx.x;
    const int lane = tid & 63;
    const int wid = tid >> 6;
    const int wm = wid >> 2, wn = wid & 3;
    const int lrow = lane & 15;
    const int lko = lane >> 4;

    const int s_r = tid >> 3;
    const int scb = ((tid & 7) * 16) ^ (((tid >> 3) & 7) << 4);
    const char* gA = xq + (size_t)(brow + s_r) * IN_F + scb;
    const char* gB = wq + (size_t)(bcol + s_r) * IN_F + scb;

    char* const sA0 = (char*)lds;
    char* const sA1 = (char*)lds + 32768;
    char* const sB0 = (char*)lds + 65536;
    char* const sB1 = (char*)lds + 98304;

    const int aBase = (wm * 128 + lrow) * 128;
    const int bBase = (wn * 64 + lrow) * 128;
    const int koff[2] = {(lko * 16) ^ ((lrow & 7) << 4),
                         ((lko * 16) | 64) ^ ((lrow & 7) << 4)};

    i32x4 acc[8][4];
#pragma unroll
    for (int mf = 0; mf < 8; ++mf)
#pragma unroll
        for (int nf = 0; nf < 4; ++nf)
#pragma unroll
            for (int q = 0; q < 4; ++q) acc[mf][nf][q] = 0;

#define STAGE_A(kk, base, half)                                                                       \
    do {                                                                                              \
        direct_load16(gA + (size_t)((half) * 128) * IN_F + (kk), (base) + (half) * 16384 + tid * 16); \
        direct_load16(gA + (size_t)((half) * 128 + 64) * IN_F + (kk),                                 \
                      (base) + (half) * 16384 + 8192 + tid * 16);                                     \
    } while (0)
#define STAGE_B(kk, base, half)                                                                       \
    do {                                                                                              \
        direct_load16(gB + (size_t)((half) * 128) * IN_F + (kk), (base) + (half) * 16384 + tid * 16); \
        direct_load16(gB + (size_t)((half) * 128 + 64) * IN_F + (kk),                                 \
                      (base) + (half) * 16384 + 8192 + tid * 16);                                     \
    } while (0)

#define READ_AL(Ab)                                                          \
    _Pragma("unroll") for (int mf = 0; mf < 4; ++mf) {                       \
        aL[mf][0] = *(const i32x4*)((Ab) + aBase + mf * 2048 + koff[0]);     \
        aL[mf][1] = *(const i32x4*)((Ab) + aBase + mf * 2048 + koff[1]);     \
    }
#define READ_AH(Ab)                                                               \
    _Pragma("unroll") for (int mf = 0; mf < 4; ++mf) {                            \
        aH[mf][0] = *(const i32x4*)((Ab) + aBase + (4 + mf) * 2048 + koff[0]);    \
        aH[mf][1] = *(const i32x4*)((Ab) + aBase + (4 + mf) * 2048 + koff[1]);    \
    }
#define READ_BL(Bb)                                                          \
    _Pragma("unroll") for (int nf = 0; nf < 2; ++nf) {                       \
        bL[nf][0] = *(const i32x4*)((Bb) + bBase + nf * 2048 + koff[0]);     \
        bL[nf][1] = *(const i32x4*)((Bb) + bBase + nf * 2048 + koff[1]);     \
    }
#define READ_BH(Bb)                                                               \
    _Pragma("unroll") for (int nf = 0; nf < 2; ++nf) {                            \
        bH[nf][0] = *(const i32x4*)((Bb) + bBase + (2 + nf) * 2048 + koff[0]);    \
        bH[nf][1] = *(const i32x4*)((Bb) + bBase + (2 + nf) * 2048 + koff[1]);    \
    }
#define QUAD(MB, NB, AF, BF)                                                  \
    do {                                                                      \
        __builtin_amdgcn_s_setprio(1);                                        \
        _Pragma("unroll") for (int mf = 0; mf < 4; ++mf)                      \
            _Pragma("unroll") for (int nf = 0; nf < 2; ++nf) {                \
            acc[(MB) + mf][(NB) + nf] =                                       \
                mfma_i8(AF[mf][0], BF[nf][0], acc[(MB) + mf][(NB) + nf]);     \
            acc[(MB) + mf][(NB) + nf] =                                       \
                mfma_i8(AF[mf][1], BF[nf][1], acc[(MB) + mf][(NB) + nf]);     \
        }                                                                     \
        __builtin_amdgcn_s_setprio(0);                                        \
    } while (0)

    STAGE_A(0, sA0, 0);
    STAGE_A(0, sA0, 1);
    STAGE_B(0, sB0, 0);
    STAGE_B(0, sB0, 1);
    STAGE_B(BKB, sB1, 0);
    STAGE_B(BKB, sB1, 1);
    VM(4);
    BAR();

    i32x4 aL[4][2], aH[4][2], bL[2][2], bH[2][2];

    for (int i = 0; i < NTILE / 2; ++i) {
        const int t = 2 * i;
        const int kk1 = (t + 1) * BKB, kk2 = (t + 2) * BKB, kk3 = (t + 3) * BKB;
        const bool pf = (t + 2 < NTILE);

        // ===== seg1 (ph1+ph2): reads of slot0 A-lo/B | stage A(t+1) | Q00,Q02 =====
        READ_AL(sA0);
        READ_BL(sB0);
        STAGE_A(kk1, sA1, 0);
        LGKM0();
        QUAD(0, 0, aL, bL);
        READ_BH(sB0);
        STAGE_A(kk1, sA1, 1);
        LGKM0();
        QUAD(0, 2, aL, bH);
        BAR();  // BAR2: all waves' sB0 reads retired -> sB0 may be overwritten

        // ===== seg2 (ph3+ph4): read A-hi | stage B(t+2)->sB0 | Q42,Q40 | collective VM =====
        READ_AH(sA0);
        if (pf) STAGE_B(kk2, sB0, 0);
        LGKM0();
        QUAD(4, 2, aH, bH);
        if (pf) {
            STAGE_B(kk2, sB0, 1);
            VM(4);  // A(t+1)+B(t+1) landed; B(t+2)'s 4 in flight
        } else {
            VM(0);
        }
        BAR();  // BAR4: VM collective + all aL/aH(sA0) reads retired -> sA0 may be overwritten
        QUAD(4, 0, aH, bL);

        // ===== seg3 (ph5+ph6): reads of slot1 | stage A(t+2)->sA0 | Q00,Q02 =====
        READ_AL(sA1);
        READ_BL(sB1);
        if (pf) STAGE_A(kk2, sA0, 0);
        LGKM0();
        QUAD(0, 0, aL, bL);
        READ_BH(sB1);
        if (pf) STAGE_A(kk2, sA0, 1);
        LGKM0();
        QUAD(0, 2, aL, bH);
        BAR();  // BAR6: all waves' sB1 reads retired -> sB1 may be overwritten

        // ===== seg4 (ph7+ph8): read A-hi(slot1) | stage B(t+3)->sB1 | Q42,Q40 | collective VM =====
        READ_AH(sA1);
        if (pf) STAGE_B(kk3, sB1, 0);
        LGKM0();
        QUAD(4, 2, aH, bH);
        if (pf) STAGE_B(kk3, sB1, 1);
        VM(4);  // A(t+2)+B(t+2) landed; B(t+3)'s 4 in flight (trivial on final iter)
        BAR();  // BAR8: VM collective + all sA1 reads retired -> next iteration safe
        QUAD(4, 0, aH, bL);
    }
#undef STAGE_A
#undef STAGE_B
#undef READ_AL
#undef READ_AH
#undef READ_BL
#undef READ_BH
#undef QUAD

    // ---- epilogue: lora tiles to LDS (bf16), scales, combine ----
    __syncthreads();
    unsigned short* tls = (unsigned short*)lds;           // [256][16] bf16 t (prescaled by 2)
    unsigned short* lls = (unsigned short*)(lds + 8192);  // [256][16] bf16 lbt
    {
        const int row = tid >> 1, h = tid & 1;
        *(s16x8*)(tls + row * 16 + h * 8) = *(const s16x8*)(tbf + (size_t)(brow + row) * RNK + h * 8);
        *(s16x8*)(lls + row * 16 + h * 8) = *(const s16x8*)(lbt + (size_t)(bcol + row) * RNK + h * 8);
    }
    __syncthreads();

    const int c0 = bcol + wn * 64 + lrow;
    const int r0base = brow + wm * 128 + lko * 4;

    s16x8 z;
#pragma unroll
    for (int e = 0; e < 8; ++e) z[e] = 0;
    s16x8 at8[8], bl8[4];
#pragma unroll
    for (int mf = 0; mf < 8; ++mf) {
        const int row = wm * 128 + mf * 16 + lrow;
        at8[mf] = (lko < 2) ? *(const s16x8*)(tls + row * 16 + lko * 8) : z;
    }
#pragma unroll
    for (int nf = 0; nf < 4; ++nf) {
        const int row = wn * 64 + nf * 16 + lrow;
        bl8[nf] = (lko < 2) ? *(const s16x8*)(lls + row * 16 + lko * 8) : z;
    }
    float ws4[4];
#pragma unroll
    for (int nf = 0; nf < 4; ++nf) ws4[nf] = wscale[c0 + nf * 16];

    const f32x4 zf = {0.f, 0.f, 0.f, 0.f};
#pragma unroll
    for (int mf = 0; mf < 8; ++mf) {
        f32x4 lor[4];
#pragma unroll
        for (int nf = 0; nf < 4; ++nf) lor[nf] = mfma16(at8[mf], bl8[nf], zf);
        const f32x4 xs4 = *(const f32x4*)(xscale + r0base + mf * 16);
#pragma unroll
        for (int q = 0; q < 4; ++q) {
            float* orow = out + (size_t)(r0base + mf * 16 + q) * OUT_F;
#pragma unroll
            for (int nf = 0; nf < 4; ++nf)
                orow[c0 + nf * 16] =
                    xs4[q] * ws4[nf] * (float)acc[mf][nf][q] + lor[nf][q];
        }
    }
}

extern "C" void kernel_launch(void* const* d_in, const int* in_sizes, int n_in,
                              void* d_out, int out_size, void* d_ws, size_t ws_size,
                              hipStream_t stream) {
    const float* x  = (const float*)d_in[0];
    const float* w  = (const float*)d_in[1];
    const float* la = (const float*)d_in[2];
    const float* lb = (const float*)d_in[3];
    float* out = (float*)d_out;

    char* ws = (char*)d_ws;
    size_t off = 0;
    char* xq = ws + off;                 off += (size_t)TOKENS * IN_F;      // 64 MiB
    char* wqb = ws + off;                off += (size_t)OUT_F * IN_F;       // 16 MiB
    unsigned short* tbf = (unsigned short*)(ws + off); off += (size_t)TOKENS * RNK * 2;  // 512 KiB
    unsigned short* lbt = (unsigned short*)(ws + off); off += (size_t)OUT_F * RNK * 2;   // 128 KiB
    float* xscale = (float*)(ws + off);  off += (size_t)TOKENS * 4;         // 64 KiB
    float* wscale = (float*)(ws + off);  off += (size_t)OUT_F * 4;          // 16 KiB
    char* laqT = ws + off;               off += (size_t)RNK * IN_F;         // 64 KiB
    float* lascale = (float*)(ws + off); off += RNK * 4;

    qd_weight_kernel<<<OUT_F, 256, 0, stream>>>(w, lb, (uint32_t*)wqb, wscale, lbt);
    laq_kernel<<<RNK, 256, 0, stream>>>(la, laqT, lascale);
    xquant_kernel<<<TOKENS / 4, 256, 0, stream>>>(x, (uint32_t*)xq, xscale);
    lora_t_kernel<<<TOKENS / 64, 256, 0, stream>>>(xq, laqT, xscale, lascale, tbf);
    gemm8p_i8_kernel<<<(TOKENS / BM) * (OUT_F / BN), 512, 0, stream>>>(
        xq, wqb, xscale, wscale, tbf, lbt, out);
}

// Round 13
// 374.975 us; speedup vs baseline: 1.2400x; 1.0105x over previous
//
#include <hip/hip_runtime.h>
#include <stdint.h>

typedef __attribute__((ext_vector_type(4))) float f32x4;
typedef __attribute__((ext_vector_type(8))) short s16x8;
typedef __attribute__((ext_vector_type(4))) int i32x4;

#define TOKENS 16384
#define IN_F 4096
#define OUT_F 4096
#define RNK 16
#define BM 256
#define BN 256
#define BKB 128               // K-tile in BYTES per row (=128 int8)
#define NTILE (IN_F / BKB)    // 32 K-tiles

static __device__ __forceinline__ unsigned short f32_to_bf16(float f) {
    uint32_t u = __builtin_bit_cast(uint32_t, f);
    uint32_t r = (u + 0x7FFFu + ((u >> 16) & 1u)) >> 16;
    return (unsigned short)r;
}

static __device__ __forceinline__ void direct_load16(const void* g, void* l) {
    __builtin_amdgcn_global_load_lds(
        (const __attribute__((address_space(1))) void*)(uintptr_t)g,
        (__attribute__((address_space(3))) void*)(uintptr_t)l,
        16, 0, 0);
}

static __device__ __forceinline__ i32x4 mfma_i8(i32x4 a, i32x4 b, i32x4 c) {
    return __builtin_amdgcn_mfma_i32_16x16x64_i8(a, b, c, 0, 0, 0);
}
static __device__ __forceinline__ f32x4 mfma16(s16x8 a, s16x8 b, f32x4 c) {
    return __builtin_amdgcn_mfma_f32_16x16x32_bf16(a, b, c, 0, 0, 0);
}

#define BAR() asm volatile("s_barrier" ::: "memory")
#define VM(n) asm volatile("s_waitcnt vmcnt(" #n ")" ::: "memory")
#define SB0() __builtin_amdgcn_sched_barrier(0)

// ---------------- Kernel A: per-row absmax int8 quant of W -> wq int8 + wscale, + lora_b transpose ----------------
__global__ __launch_bounds__(256) void qd_weight_kernel(const float* __restrict__ w,
                                                        const float* __restrict__ lb,
                                                        uint32_t* __restrict__ wq,
                                                        float* __restrict__ wscale,
                                                        unsigned short* __restrict__ lbt) {
    const int row = blockIdx.x;
    const int tid = threadIdx.x;
    const float* wr = w + (size_t)row * IN_F;
    f32x4 v[4];
#pragma unroll
    for (int p = 0; p < 4; ++p)
        v[p] = *(const f32x4*)(wr + (size_t)(tid + p * 256) * 4);
    float m = 0.f;
#pragma unroll
    for (int p = 0; p < 4; ++p)
#pragma unroll
        for (int e = 0; e < 4; ++e)
            m = fmaxf(m, fabsf(v[p][e]));
#pragma unroll
    for (int off = 1; off < 64; off <<= 1)
        m = fmaxf(m, __shfl_xor(m, off, 64));
    __shared__ float red[4];
    if ((tid & 63) == 0) red[tid >> 6] = m;
    __syncthreads();
    m = fmaxf(fmaxf(red[0], red[1]), fmaxf(red[2], red[3]));
    const float scale = m * (1.0f / 127.0f);
    const float denom = scale + 1e-8f;
#pragma unroll
    for (int p = 0; p < 4; ++p) {
        uint32_t pack = 0;
#pragma unroll
        for (int e = 0; e < 4; ++e) {
            float q = rintf(v[p][e] / denom);  // RNE, matches jnp.round
            q = fminf(fmaxf(q, -128.f), 127.f);
            pack |= ((uint32_t)(uint8_t)(int)q) << (8 * e);
        }
        wq[(size_t)row * (IN_F / 4) + tid + p * 256] = pack;
    }
    if (tid == 0) wscale[row] = scale;
    if (tid < RNK)
        lbt[(size_t)row * RNK + tid] = f32_to_bf16(lb[(size_t)tid * OUT_F + row]);
}

// ---------------- Kernel A2: quantize lora_a per-r column -> la_qT[16][4096] int8 + lascale ----------------
__global__ __launch_bounds__(256) void laq_kernel(const float* __restrict__ la,
                                                  char* __restrict__ laqT,
                                                  float* __restrict__ lascale) {
    const int r = blockIdx.x;
    const int tid = threadIdx.x;
    float v[16];
#pragma unroll
    for (int j = 0; j < 16; ++j)
        v[j] = la[(size_t)(tid + j * 256) * RNK + r];
    float m = 0.f;
#pragma unroll
    for (int j = 0; j < 16; ++j) m = fmaxf(m, fabsf(v[j]));
#pragma unroll
    for (int off = 1; off < 64; off <<= 1)
        m = fmaxf(m, __shfl_xor(m, off, 64));
    __shared__ float red[4];
    if ((tid & 63) == 0) red[tid >> 6] = m;
    __syncthreads();
    m = fmaxf(fmaxf(red[0], red[1]), fmaxf(red[2], red[3]));
    m = fmaxf(m, 1e-12f);
    const float inv = 127.0f / m;
    if (tid == 0) lascale[r] = m * (1.0f / 127.0f);
#pragma unroll
    for (int j = 0; j < 16; ++j) {
        float q = fminf(fmaxf(rintf(v[j] * inv), -128.f), 127.f);
        laqT[(size_t)r * IN_F + tid + j * 256] = (char)(int)q;
    }
}

// ------------- Kernel B1: per-token absmax + int8 quantize (x read once, register-cached) -------------
__global__ __launch_bounds__(256) void xquant_kernel(const float* __restrict__ x,
                                                     uint32_t* __restrict__ xqw,
                                                     float* __restrict__ xscale) {
    const int lane = threadIdx.x & 63;
    const int t = blockIdx.x * 4 + (threadIdx.x >> 6);
    const float* xr = x + (size_t)t * IN_F;

    f32x4 xv[16];
#pragma unroll
    for (int j = 0; j < 16; ++j)
        xv[j] = *(const f32x4*)(xr + j * 256 + lane * 4);

    float m = 0.f;
#pragma unroll
    for (int j = 0; j < 16; ++j)
#pragma unroll
        for (int e = 0; e < 4; ++e) m = fmaxf(m, fabsf(xv[j][e]));
#pragma unroll
    for (int off = 1; off < 64; off <<= 1)
        m = fmaxf(m, __shfl_xor(m, off, 64));
    m = fmaxf(m, 1e-6f);
    const float inv = 127.0f / m;
    if (lane == 0) xscale[t] = m * (1.0f / 127.0f);

#pragma unroll
    for (int j = 0; j < 16; ++j) {
        uint32_t pack = 0;
#pragma unroll
        for (int e = 0; e < 4; ++e) {
            float q = fminf(fmaxf(rintf(xv[j][e] * inv), -128.f), 127.f);
            pack |= ((uint32_t)(uint8_t)(int)q) << (8 * e);
        }
        xqw[(size_t)t * (IN_F / 4) + j * 64 + lane] = pack;
    }
}

// ------------- Kernel B2: t = bf16(2 * xscale * lascale * (xq @ laqT^T)) via i8 MFMA -------------
__global__ __launch_bounds__(256) void lora_t_kernel(const char* __restrict__ xq,
                                                     const char* __restrict__ laqT,
                                                     const float* __restrict__ xscale,
                                                     const float* __restrict__ lascale,
                                                     unsigned short* __restrict__ tbf) {
    const int tid = threadIdx.x;
    const int lane = tid & 63;
    const int wid = tid >> 6;
    const int t0 = blockIdx.x * 64 + wid * 16;
    const int lrow = lane & 15;
    const int lko = lane >> 4;

    const char* pA = xq + (size_t)(t0 + lrow) * IN_F + lko * 16;
    const char* pB = laqT + (size_t)lrow * IN_F + lko * 16;

    i32x4 acc = {0, 0, 0, 0};
#pragma unroll 8
    for (int it = 0; it < IN_F / 64; ++it) {
        i32x4 a = *(const i32x4*)(pA + it * 64);
        i32x4 b = *(const i32x4*)(pB + it * 64);
        acc = mfma_i8(a, b, acc);
    }

    const float ls = lascale[lrow];
    const f32x4 xs = *(const f32x4*)(xscale + t0 + lko * 4);
#pragma unroll
    for (int q = 0; q < 4; ++q)
        tbf[(size_t)(t0 + lko * 4 + q) * RNK + lrow] =
            f32_to_bf16(2.0f * xs[q] * ls * (float)acc[q]);
}

// ------------- Kernel C: minimal-barrier 256x256 i8 MFMA GEMM, COMPILER-SCHEDULED lgkm -------------
// R12 structure with all explicit lgkmcnt drains removed: ds_reads are plain C++ loads, so the
// compiler emits counted lgkmcnt before each dependent MFMA and may interleave read-issue with
// MFMAs (the m97-documented behavior my LGKM0+sched_barrier pin was defeating).
// Correctness pin: sched_barrier(0) immediately before each closing s_barrier keeps every read's
// first consumer (QUAD) pre-barrier -> reads retired before the buffer is DMA-overwritten.
// VM ledger / staging / swizzle identical to the R9-proven version.
__global__ __launch_bounds__(512, 2) void gemm8p_i8_kernel(const char* __restrict__ xq,
                                                           const char* __restrict__ wq,
                                                           const float* __restrict__ xscale,
                                                           const float* __restrict__ wscale,
                                                           const unsigned short* __restrict__ tbf,
                                                           const unsigned short* __restrict__ lbt,
                                                           float* __restrict__ out) {
    __shared__ char lds[131072];  // A-slot0 | A-slot1 | B-slot0 | B-slot1, 32KB each

    const int bid = blockIdx.x;
    const int swz = (bid & 7) * 128 + (bid >> 3);  // bijective XCD swizzle (1024 % 8 == 0)
    const int tm = swz & 63, tn = swz >> 6;
    const int brow = tm * BM, bcol = tn * BN;

    const int tid = threadIdx.x;
    const int lane = tid & 63;
    const int wid = tid >> 6;
    const int wm = wid >> 2, wn = wid & 3;
    const int lrow = lane & 15;
    const int lko = lane >> 4;

    const int s_r = tid >> 3;
    const int scb = ((tid & 7) * 16) ^ (((tid >> 3) & 7) << 4);
    const char* gA = xq + (size_t)(brow + s_r) * IN_F + scb;
    const char* gB = wq + (size_t)(bcol + s_r) * IN_F + scb;

    char* const sA0 = (char*)lds;
    char* const sA1 = (char*)lds + 32768;
    char* const sB0 = (char*)lds + 65536;
    char* const sB1 = (char*)lds + 98304;

    const int aBase = (wm * 128 + lrow) * 128;
    const int bBase = (wn * 64 + lrow) * 128;
    const int koff[2] = {(lko * 16) ^ ((lrow & 7) << 4),
                         ((lko * 16) | 64) ^ ((lrow & 7) << 4)};

    i32x4 acc[8][4];
#pragma unroll
    for (int mf = 0; mf < 8; ++mf)
#pragma unroll
        for (int nf = 0; nf < 4; ++nf)
#pragma unroll
            for (int q = 0; q < 4; ++q) acc[mf][nf][q] = 0;

#define STAGE_A(kk, base, half)                                                                       \
    do {                                                                                              \
        direct_load16(gA + (size_t)((half) * 128) * IN_F + (kk), (base) + (half) * 16384 + tid * 16); \
        direct_load16(gA + (size_t)((half) * 128 + 64) * IN_F + (kk),                                 \
                      (base) + (half) * 16384 + 8192 + tid * 16);                                     \
    } while (0)
#define STAGE_B(kk, base, half)                                                                       \
    do {                                                                                              \
        direct_load16(gB + (size_t)((half) * 128) * IN_F + (kk), (base) + (half) * 16384 + tid * 16); \
        direct_load16(gB + (size_t)((half) * 128 + 64) * IN_F + (kk),                                 \
                      (base) + (half) * 16384 + 8192 + tid * 16);                                     \
    } while (0)

#define READ_AL(Ab)                                                          \
    _Pragma("unroll") for (int mf = 0; mf < 4; ++mf) {                       \
        aL[mf][0] = *(const i32x4*)((Ab) + aBase + mf * 2048 + koff[0]);     \
        aL[mf][1] = *(const i32x4*)((Ab) + aBase + mf * 2048 + koff[1]);     \
    }
#define READ_AH(Ab)                                                               \
    _Pragma("unroll") for (int mf = 0; mf < 4; ++mf) {                            \
        aH[mf][0] = *(const i32x4*)((Ab) + aBase + (4 + mf) * 2048 + koff[0]);    \
        aH[mf][1] = *(const i32x4*)((Ab) + aBase + (4 + mf) * 2048 + koff[1]);    \
    }
#define READ_BL(Bb)                                                          \
    _Pragma("unroll") for (int nf = 0; nf < 2; ++nf) {                       \
        bL[nf][0] = *(const i32x4*)((Bb) + bBase + nf * 2048 + koff[0]);     \
        bL[nf][1] = *(const i32x4*)((Bb) + bBase + nf * 2048 + koff[1]);     \
    }
#define READ_BH(Bb)                                                               \
    _Pragma("unroll") for (int nf = 0; nf < 2; ++nf) {                            \
        bH[nf][0] = *(const i32x4*)((Bb) + bBase + (2 + nf) * 2048 + koff[0]);    \
        bH[nf][1] = *(const i32x4*)((Bb) + bBase + (2 + nf) * 2048 + koff[1]);    \
    }
#define QUAD(MB, NB, AF, BF)                                                  \
    do {                                                                      \
        __builtin_amdgcn_s_setprio(1);                                        \
        _Pragma("unroll") for (int mf = 0; mf < 4; ++mf)                      \
            _Pragma("unroll") for (int nf = 0; nf < 2; ++nf) {                \
            acc[(MB) + mf][(NB) + nf] =                                       \
                mfma_i8(AF[mf][0], BF[nf][0], acc[(MB) + mf][(NB) + nf]);     \
            acc[(MB) + mf][(NB) + nf] =                                       \
                mfma_i8(AF[mf][1], BF[nf][1], acc[(MB) + mf][(NB) + nf]);     \
        }                                                                     \
        __builtin_amdgcn_s_setprio(0);                                        \
    } while (0)

    STAGE_A(0, sA0, 0);
    STAGE_A(0, sA0, 1);
    STAGE_B(0, sB0, 0);
    STAGE_B(0, sB0, 1);
    STAGE_B(BKB, sB1, 0);
    STAGE_B(BKB, sB1, 1);
    VM(4);
    BAR();

    i32x4 aL[4][2], aH[4][2], bL[2][2], bH[2][2];

    for (int i = 0; i < NTILE / 2; ++i) {
        const int t = 2 * i;
        const int kk1 = (t + 1) * BKB, kk2 = (t + 2) * BKB, kk3 = (t + 3) * BKB;
        const bool pf = (t + 2 < NTILE);

        // ===== seg1: reads of slot0 A-lo/B | stage A(t+1) | Q00,Q02 (compiler-counted lgkm) =====
        READ_AL(sA0);
        READ_BL(sB0);
        STAGE_A(kk1, sA1, 0);
        QUAD(0, 0, aL, bL);
        READ_BH(sB0);
        STAGE_A(kk1, sA1, 1);
        QUAD(0, 2, aL, bH);
        SB0();
        BAR();  // BAR2: sB0 reads consumed (pinned above) -> sB0 may be overwritten

        // ===== seg2: read A-hi | stage B(t+2)->sB0 | Q42 | collective VM =====
        READ_AH(sA0);
        if (pf) STAGE_B(kk2, sB0, 0);
        QUAD(4, 2, aH, bH);
        if (pf) {
            STAGE_B(kk2, sB0, 1);
            VM(4);  // A(t+1)+B(t+1) landed; B(t+2)'s 4 in flight
        } else {
            VM(0);
        }
        SB0();
        BAR();  // BAR4: VM collective + sA0 reads consumed -> sA0 may be overwritten
        QUAD(4, 0, aH, bL);  // register-only (aH,bL already retired) — overlaps seg3 reads

        // ===== seg3: reads of slot1 | stage A(t+2)->sA0 | Q00,Q02 =====
        READ_AL(sA1);
        READ_BL(sB1);
        if (pf) STAGE_A(kk2, sA0, 0);
        QUAD(0, 0, aL, bL);
        READ_BH(sB1);
        if (pf) STAGE_A(kk2, sA0, 1);
        QUAD(0, 2, aL, bH);
        SB0();
        BAR();  // BAR6: sB1 reads consumed -> sB1 may be overwritten

        // ===== seg4: read A-hi(slot1) | stage B(t+3)->sB1 | Q42 | collective VM =====
        READ_AH(sA1);
        if (pf) STAGE_B(kk3, sB1, 0);
        QUAD(4, 2, aH, bH);
        if (pf) STAGE_B(kk3, sB1, 1);
        VM(4);  // A(t+2)+B(t+2) landed; B(t+3)'s 4 in flight (trivial on final iter)
        SB0();
        BAR();  // BAR8: VM collective + sA1 reads consumed -> next iteration safe
        QUAD(4, 0, aH, bL);
    }
#undef STAGE_A
#undef STAGE_B
#undef READ_AL
#undef READ_AH
#undef READ_BL
#undef READ_BH
#undef QUAD

    // ---- epilogue: lora tiles to LDS (bf16), scales, combine ----
    __syncthreads();
    unsigned short* tls = (unsigned short*)lds;           // [256][16] bf16 t (prescaled by 2)
    unsigned short* lls = (unsigned short*)(lds + 8192);  // [256][16] bf16 lbt
    {
        const int row = tid >> 1, h = tid & 1;
        *(s16x8*)(tls + row * 16 + h * 8) = *(const s16x8*)(tbf + (size_t)(brow + row) * RNK + h * 8);
        *(s16x8*)(lls + row * 16 + h * 8) = *(const s16x8*)(lbt + (size_t)(bcol + row) * RNK + h * 8);
    }
    __syncthreads();

    const int c0 = bcol + wn * 64 + lrow;
    const int r0base = brow + wm * 128 + lko * 4;

    s16x8 z;
#pragma unroll
    for (int e = 0; e < 8; ++e) z[e] = 0;
    s16x8 at8[8], bl8[4];
#pragma unroll
    for (int mf = 0; mf < 8; ++mf) {
        const int row = wm * 128 + mf * 16 + lrow;
        at8[mf] = (lko < 2) ? *(const s16x8*)(tls + row * 16 + lko * 8) : z;
    }
#pragma unroll
    for (int nf = 0; nf < 4; ++nf) {
        const int row = wn * 64 + nf * 16 + lrow;
        bl8[nf] = (lko < 2) ? *(const s16x8*)(lls + row * 16 + lko * 8) : z;
    }
    float ws4[4];
#pragma unroll
    for (int nf = 0; nf < 4; ++nf) ws4[nf] = wscale[c0 + nf * 16];

    const f32x4 zf = {0.f, 0.f, 0.f, 0.f};
#pragma unroll
    for (int mf = 0; mf < 8; ++mf) {
        f32x4 lor[4];
#pragma unroll
        for (int nf = 0; nf < 4; ++nf) lor[nf] = mfma16(at8[mf], bl8[nf], zf);
        const f32x4 xs4 = *(const f32x4*)(xscale + r0base + mf * 16);
#pragma unroll
        for (int q = 0; q < 4; ++q) {
            float* orow = out + (size_t)(r0base + mf * 16 + q) * OUT_F;
#pragma unroll
            for (int nf = 0; nf < 4; ++nf)
                orow[c0 + nf * 16] =
                    xs4[q] * ws4[nf] * (float)acc[mf][nf][q] + lor[nf][q];
        }
    }
}

extern "C" void kernel_launch(void* const* d_in, const int* in_sizes, int n_in,
                              void* d_out, int out_size, void* d_ws, size_t ws_size,
                              hipStream_t stream) {
    const float* x  = (const float*)d_in[0];
    const float* w  = (const float*)d_in[1];
    const float* la = (const float*)d_in[2];
    const float* lb = (const float*)d_in[3];
    float* out = (float*)d_out;

    char* ws = (char*)d_ws;
    size_t off = 0;
    char* xq = ws + off;                 off += (size_t)TOKENS * IN_F;      // 64 MiB
    char* wqb = ws + off;                off += (size_t)OUT_F * IN_F;       // 16 MiB
    unsigned short* tbf = (unsigned short*)(ws + off); off += (size_t)TOKENS * RNK * 2;  // 512 KiB
    unsigned short* lbt = (unsigned short*)(ws + off); off += (size_t)OUT_F * RNK * 2;   // 128 KiB
    float* xscale = (float*)(ws + off);  off += (size_t)TOKENS * 4;         // 64 KiB
    float* wscale = (float*)(ws + off);  off += (size_t)OUT_F * 4;          // 16 KiB
    char* laqT = ws + off;               off += (size_t)RNK * IN_F;         // 64 KiB
    float* lascale = (float*)(ws + off); off += RNK * 4;

    qd_weight_kernel<<<OUT_F, 256, 0, stream>>>(w, lb, (uint32_t*)wqb, wscale, lbt);
    laq_kernel<<<RNK, 256, 0, stream>>>(la, laqT, lascale);
    xquant_kernel<<<TOKENS / 4, 256, 0, stream>>>(x, (uint32_t*)xq, xscale);
    lora_t_kernel<<<TOKENS / 64, 256, 0, stream>>>(xq, laqT, xscale, lascale, tbf);
    gemm8p_i8_kernel<<<(TOKENS / BM) * (OUT_F / BN), 512, 0, stream>>>(
        xq, wqb, xscale, wscale, tbf, lbt, out);
}